// Round 14
// baseline (45.314 us; speedup 1.0000x reference)
//
#include <hip/hip_runtime.h>
#include <stdint.h>

#define NCLS 14
#define BATCH 2
#define NUM_BINS (BATCH * NCLS)   // 28
#define KSPREAD 64                // per-bin atomic spread factor

// d_ws layout: float fsum[NUM_BINS*KSPREAD] | int fcnt[NUM_BINS*KSPREAD]

__global__ void kd14_zero(float* __restrict__ fsum, int* __restrict__ fcnt) {
    int i = blockIdx.x * blockDim.x + threadIdx.x;   // grid covers 1792 exactly
    fsum[i] = 0.0f;
    fcnt[i] = 0;
}

// __launch_bounds__(256, 1): min 1 wave/EU -> VGPR cap 512, NOT the default
// 8-wave target whose 64-VGPR cap forced the 28 asm destinations to spill
// (spill-of-load-dest serializes the loads back into batches of 7).
__global__ __launch_bounds__(256, 1) void kd14_kl(
        const float* __restrict__ S, const float* __restrict__ T,
        const int* __restrict__ gt,
        float* __restrict__ fsum, int* __restrict__ fcnt,
        int N /* voxels per batch image */) {
    // Per-wave sum bins (contention cut); counts via ballot (no atomics).
    __shared__ float lsum[4][16];
    __shared__ int lcnt[4][16];
    const int tid = threadIdx.x;
    const int wave = tid >> 6, lane = tid & 63;
    if (tid < 64) { lsum[tid >> 4][tid & 15] = 0.0f; lcnt[tid >> 4][tid & 15] = 0; }
    __syncthreads();

    // b from blockIdx only -> block-uniform -> SGPR channel bases (saddr form).
    const int b = ((unsigned)blockIdx.x * 1024u >= (unsigned)N) ? 1 : 0;
    const int gid = blockIdx.x * blockDim.x + tid;
    const int v0 = gid * 4;                       // 4 voxels per thread
    const int n = v0 - b * N;

    const float* Sb = S + (size_t)b * NCLS * N;   // uniform (SGPR pair)
    const float* Tb = T + (size_t)b * NCLS * N;   // uniform (SGPR pair)
    const uint32_t voff = (uint32_t)n * 4u;       // per-lane byte offset

    float4 sv[NCLS], tv[NCLS];

    // ---- Force 28 independent dwordx4 loads in flight (28 KB/wave). ----
    asm volatile(
        "global_load_dwordx4 %[d0], %[vo], %[p0]\n\t"
        "global_load_dwordx4 %[d1], %[vo], %[p1]\n\t"
        "global_load_dwordx4 %[d2], %[vo], %[p2]\n\t"
        "global_load_dwordx4 %[d3], %[vo], %[p3]\n\t"
        "global_load_dwordx4 %[d4], %[vo], %[p4]\n\t"
        "global_load_dwordx4 %[d5], %[vo], %[p5]\n\t"
        "global_load_dwordx4 %[d6], %[vo], %[p6]\n\t"
        : [d0]"=v"(sv[0]), [d1]"=v"(sv[1]), [d2]"=v"(sv[2]), [d3]"=v"(sv[3]),
          [d4]"=v"(sv[4]), [d5]"=v"(sv[5]), [d6]"=v"(sv[6])
        : [vo]"v"(voff),
          [p0]"s"(Sb + 0*(size_t)N), [p1]"s"(Sb + 1*(size_t)N),
          [p2]"s"(Sb + 2*(size_t)N), [p3]"s"(Sb + 3*(size_t)N),
          [p4]"s"(Sb + 4*(size_t)N), [p5]"s"(Sb + 5*(size_t)N),
          [p6]"s"(Sb + 6*(size_t)N));
    asm volatile(
        "global_load_dwordx4 %[d0], %[vo], %[p0]\n\t"
        "global_load_dwordx4 %[d1], %[vo], %[p1]\n\t"
        "global_load_dwordx4 %[d2], %[vo], %[p2]\n\t"
        "global_load_dwordx4 %[d3], %[vo], %[p3]\n\t"
        "global_load_dwordx4 %[d4], %[vo], %[p4]\n\t"
        "global_load_dwordx4 %[d5], %[vo], %[p5]\n\t"
        "global_load_dwordx4 %[d6], %[vo], %[p6]\n\t"
        : [d0]"=v"(sv[7]), [d1]"=v"(sv[8]), [d2]"=v"(sv[9]), [d3]"=v"(sv[10]),
          [d4]"=v"(sv[11]), [d5]"=v"(sv[12]), [d6]"=v"(sv[13])
        : [vo]"v"(voff),
          [p0]"s"(Sb + 7*(size_t)N), [p1]"s"(Sb + 8*(size_t)N),
          [p2]"s"(Sb + 9*(size_t)N), [p3]"s"(Sb + 10*(size_t)N),
          [p4]"s"(Sb + 11*(size_t)N), [p5]"s"(Sb + 12*(size_t)N),
          [p6]"s"(Sb + 13*(size_t)N));
    asm volatile(
        "global_load_dwordx4 %[d0], %[vo], %[p0]\n\t"
        "global_load_dwordx4 %[d1], %[vo], %[p1]\n\t"
        "global_load_dwordx4 %[d2], %[vo], %[p2]\n\t"
        "global_load_dwordx4 %[d3], %[vo], %[p3]\n\t"
        "global_load_dwordx4 %[d4], %[vo], %[p4]\n\t"
        "global_load_dwordx4 %[d5], %[vo], %[p5]\n\t"
        "global_load_dwordx4 %[d6], %[vo], %[p6]\n\t"
        : [d0]"=v"(tv[0]), [d1]"=v"(tv[1]), [d2]"=v"(tv[2]), [d3]"=v"(tv[3]),
          [d4]"=v"(tv[4]), [d5]"=v"(tv[5]), [d6]"=v"(tv[6])
        : [vo]"v"(voff),
          [p0]"s"(Tb + 0*(size_t)N), [p1]"s"(Tb + 1*(size_t)N),
          [p2]"s"(Tb + 2*(size_t)N), [p3]"s"(Tb + 3*(size_t)N),
          [p4]"s"(Tb + 4*(size_t)N), [p5]"s"(Tb + 5*(size_t)N),
          [p6]"s"(Tb + 6*(size_t)N));
    asm volatile(
        "global_load_dwordx4 %[d0], %[vo], %[p0]\n\t"
        "global_load_dwordx4 %[d1], %[vo], %[p1]\n\t"
        "global_load_dwordx4 %[d2], %[vo], %[p2]\n\t"
        "global_load_dwordx4 %[d3], %[vo], %[p3]\n\t"
        "global_load_dwordx4 %[d4], %[vo], %[p4]\n\t"
        "global_load_dwordx4 %[d5], %[vo], %[p5]\n\t"
        "global_load_dwordx4 %[d6], %[vo], %[p6]\n\t"
        : [d0]"=v"(tv[7]), [d1]"=v"(tv[8]), [d2]"=v"(tv[9]), [d3]"=v"(tv[10]),
          [d4]"=v"(tv[11]), [d5]"=v"(tv[12]), [d6]"=v"(tv[13])
        : [vo]"v"(voff),
          [p0]"s"(Tb + 7*(size_t)N), [p1]"s"(Tb + 8*(size_t)N),
          [p2]"s"(Tb + 9*(size_t)N), [p3]"s"(Tb + 10*(size_t)N),
          [p4]"s"(Tb + 11*(size_t)N), [p5]"s"(Tb + 12*(size_t)N),
          [p6]"s"(Tb + 13*(size_t)N));

    int4 g = *reinterpret_cast<const int4*>(gt + v0);

    // Drain all asm loads; sched_barrier(0) fences register-only consumers
    // below the wait (guide rule #18).
    asm volatile("s_waitcnt vmcnt(0)" ::: "memory");
    __builtin_amdgcn_sched_barrier(0);

    float Zs[4] = {0,0,0,0}, Zt[4] = {0,0,0,0};
    float At[4] = {0,0,0,0}, As[4] = {0,0,0,0};
#pragma unroll
    for (int c = 0; c < NCLS; ++c) {
        float s[4] = {sv[c].x, sv[c].y, sv[c].z, sv[c].w};
        float t[4] = {tv[c].x, tv[c].y, tv[c].z, tv[c].w};
#pragma unroll
        for (int v = 0; v < 4; ++v) {
            float et = __expf(t[v]);
            Zt[v] += et;
            At[v] = fmaf(et, t[v], At[v]);
            As[v] = fmaf(et, s[v], As[v]);
            Zs[v] += __expf(s[v]);
        }
    }

    int cls[4];
    cls[0] = min(max(g.x, 0), NCLS - 1);
    cls[1] = min(max(g.y, 0), NCLS - 1);
    cls[2] = min(max(g.z, 0), NCLS - 1);
    cls[3] = min(max(g.w, 0), NCLS - 1);

    // Sums: per-wave LDS atomics.
#pragma unroll
    for (int v = 0; v < 4; ++v) {
        float kl = (At[v] - As[v]) / Zt[v] - __logf(Zt[v]) + __logf(Zs[v]);
        atomicAdd(&lsum[wave][cls[v]], kl);
    }
    // Counts: ballot + popcount, no atomics.
#pragma unroll
    for (int c = 0; c < NCLS; ++c) {
        int nvc = 0;
#pragma unroll
        for (int v = 0; v < 4; ++v)
            nvc += __popcll(__ballot(cls[v] == c));
        if (lane == 0) lcnt[wave][c] = nvc;
    }

    __syncthreads();
    // Only 14 bins live per block (b uniform): 28 global atomics total.
    if (tid < NCLS) {
        float s = lsum[0][tid] + lsum[1][tid] + lsum[2][tid] + lsum[3][tid];
        int nn = lcnt[0][tid] + lcnt[1][tid] + lcnt[2][tid] + lcnt[3][tid];
        const int slot = blockIdx.x & (KSPREAD - 1);
        const int bin = b * NCLS + tid;
        atomicAdd(&fsum[bin * KSPREAD + slot], s);
        atomicAdd(&fcnt[bin * KSPREAD + slot], nn);
    }
}

__global__ void kd14_final(const float* __restrict__ fsum,
                           const int* __restrict__ fcnt,
                           float* __restrict__ out) {
    __shared__ float terms[64];
    const int t = threadIdx.x;
    float term = 0.0f;
    if (t < NUM_BINS) {
        const float4* fp = reinterpret_cast<const float4*>(fsum + t * KSPREAD);
        const int4* cp = reinterpret_cast<const int4*>(fcnt + t * KSPREAD);
        float s = 0.0f; int n = 0;
#pragma unroll
        for (int i = 0; i < KSPREAD / 4; ++i) {   // fully unrolled: 32 indep loads
            float4 v = fp[i]; s += (v.x + v.y) + (v.z + v.w);
            int4 c = cp[i];   n += (c.x + c.y) + (c.z + c.w);
        }
        const int cls = t % NCLS;   // bin = b*NCLS + cls
        if (cls != 0 && n > 0) term = s / ((float)NCLS * (float)n);
    }
    terms[t] = term;
    __syncthreads();
    if (t == 0) {
        float loss = 0.0f;
#pragma unroll
        for (int i = 0; i < 64; ++i) loss += terms[i];
        out[0] = loss;   // TAU^2 = 1, LOSS_WEIGHT = 1
    }
}

extern "C" void kernel_launch(void* const* d_in, const int* in_sizes, int n_in,
                              void* d_out, int out_size, void* d_ws, size_t ws_size,
                              hipStream_t stream) {
    const float* S = (const float*)d_in[0];
    const float* T = (const float*)d_in[1];
    const int* gt = (const int*)d_in[2];
    float* out = (float*)d_out;

    float* fsum = (float*)d_ws;
    int* fcnt = (int*)((char*)d_ws + NUM_BINS * KSPREAD * sizeof(float));

    const int totalVox = in_sizes[2];       // 1,769,472 = 1728 * 1024
    const int N = totalVox / BATCH;         // 884,736 (divisible by 1024)

    const int block = 256;
    const int grid = totalVox / (block * 4);  // 1728 blocks, 4 voxels/thread

    kd14_zero<<<(NUM_BINS * KSPREAD) / 256, 256, 0, stream>>>(fsum, fcnt);  // 7 blocks
    kd14_kl<<<grid, block, 0, stream>>>(S, T, gt, fsum, fcnt, N);
    kd14_final<<<1, 64, 0, stream>>>(fsum, fcnt, out);
}

// Round 15
// 44.475 us; speedup vs baseline: 1.0189x; 1.0189x over previous
//
#include <hip/hip_runtime.h>
#include <stdint.h>

#define NCLS 14
#define BATCH 2
#define NUM_BINS (BATCH * NCLS)   // 28
#define KSPREAD 128               // per-bin spread: 3456 blocks -> 27 per line

// d_ws layout: float fsum[NUM_BINS*KSPREAD] | int fcnt[NUM_BINS*KSPREAD]

__global__ void kd15_zero(float* __restrict__ fsum, int* __restrict__ fcnt) {
    int i = blockIdx.x * blockDim.x + threadIdx.x;   // grid covers 3584 exactly
    fsum[i] = 0.0f;
    fcnt[i] = 0;
}

// VPT=2: double the block count (3456) -> ~2x resident waves. MLP via TLP:
// the wave scheduler interleaves many waves' load batches even though the
// register allocator serializes each wave's 28 loads into batches of ~7.
__global__ __launch_bounds__(256) void kd15_kl(
        const float* __restrict__ S, const float* __restrict__ T,
        const int* __restrict__ gt,
        float* __restrict__ fsum, int* __restrict__ fcnt,
        int N /* voxels per batch image */) {
    __shared__ float lsum[4][16];
    __shared__ int lcnt[4][16];
    const int tid = threadIdx.x;
    const int wave = tid >> 6, lane = tid & 63;
    if (tid < 64) { lsum[tid >> 4][tid & 15] = 0.0f; lcnt[tid >> 4][tid & 15] = 0; }
    __syncthreads();

    // b from blockIdx only -> block-uniform -> SGPR channel bases (saddr form).
    // Block covers 512 voxels; N % 512 == 0 so no batch straddle.
    const int b = ((unsigned)blockIdx.x * 512u >= (unsigned)N) ? 1 : 0;
    const int gid = blockIdx.x * blockDim.x + tid;
    const int v0 = gid * 2;                       // 2 voxels per thread
    const int n = v0 - b * N;

    const float* Sb = S + (size_t)b * NCLS * N;   // uniform (SGPR pair)
    const float* Tb = T + (size_t)b * NCLS * N;   // uniform (SGPR pair)
    const uint32_t voff = (uint32_t)n * 4u;       // per-lane byte offset

    float2 sv[NCLS], tv[NCLS];

    // ---- 28 dwordx2 loads; asm keeps issue order dense, TLP provides MLP ----
    asm volatile(
        "global_load_dwordx2 %[d0], %[vo], %[p0]\n\t"
        "global_load_dwordx2 %[d1], %[vo], %[p1]\n\t"
        "global_load_dwordx2 %[d2], %[vo], %[p2]\n\t"
        "global_load_dwordx2 %[d3], %[vo], %[p3]\n\t"
        "global_load_dwordx2 %[d4], %[vo], %[p4]\n\t"
        "global_load_dwordx2 %[d5], %[vo], %[p5]\n\t"
        "global_load_dwordx2 %[d6], %[vo], %[p6]\n\t"
        : [d0]"=v"(sv[0]), [d1]"=v"(sv[1]), [d2]"=v"(sv[2]), [d3]"=v"(sv[3]),
          [d4]"=v"(sv[4]), [d5]"=v"(sv[5]), [d6]"=v"(sv[6])
        : [vo]"v"(voff),
          [p0]"s"(Sb + 0*(size_t)N), [p1]"s"(Sb + 1*(size_t)N),
          [p2]"s"(Sb + 2*(size_t)N), [p3]"s"(Sb + 3*(size_t)N),
          [p4]"s"(Sb + 4*(size_t)N), [p5]"s"(Sb + 5*(size_t)N),
          [p6]"s"(Sb + 6*(size_t)N));
    asm volatile(
        "global_load_dwordx2 %[d0], %[vo], %[p0]\n\t"
        "global_load_dwordx2 %[d1], %[vo], %[p1]\n\t"
        "global_load_dwordx2 %[d2], %[vo], %[p2]\n\t"
        "global_load_dwordx2 %[d3], %[vo], %[p3]\n\t"
        "global_load_dwordx2 %[d4], %[vo], %[p4]\n\t"
        "global_load_dwordx2 %[d5], %[vo], %[p5]\n\t"
        "global_load_dwordx2 %[d6], %[vo], %[p6]\n\t"
        : [d0]"=v"(sv[7]), [d1]"=v"(sv[8]), [d2]"=v"(sv[9]), [d3]"=v"(sv[10]),
          [d4]"=v"(sv[11]), [d5]"=v"(sv[12]), [d6]"=v"(sv[13])
        : [vo]"v"(voff),
          [p0]"s"(Sb + 7*(size_t)N), [p1]"s"(Sb + 8*(size_t)N),
          [p2]"s"(Sb + 9*(size_t)N), [p3]"s"(Sb + 10*(size_t)N),
          [p4]"s"(Sb + 11*(size_t)N), [p5]"s"(Sb + 12*(size_t)N),
          [p6]"s"(Sb + 13*(size_t)N));
    asm volatile(
        "global_load_dwordx2 %[d0], %[vo], %[p0]\n\t"
        "global_load_dwordx2 %[d1], %[vo], %[p1]\n\t"
        "global_load_dwordx2 %[d2], %[vo], %[p2]\n\t"
        "global_load_dwordx2 %[d3], %[vo], %[p3]\n\t"
        "global_load_dwordx2 %[d4], %[vo], %[p4]\n\t"
        "global_load_dwordx2 %[d5], %[vo], %[p5]\n\t"
        "global_load_dwordx2 %[d6], %[vo], %[p6]\n\t"
        : [d0]"=v"(tv[0]), [d1]"=v"(tv[1]), [d2]"=v"(tv[2]), [d3]"=v"(tv[3]),
          [d4]"=v"(tv[4]), [d5]"=v"(tv[5]), [d6]"=v"(tv[6])
        : [vo]"v"(voff),
          [p0]"s"(Tb + 0*(size_t)N), [p1]"s"(Tb + 1*(size_t)N),
          [p2]"s"(Tb + 2*(size_t)N), [p3]"s"(Tb + 3*(size_t)N),
          [p4]"s"(Tb + 4*(size_t)N), [p5]"s"(Tb + 5*(size_t)N),
          [p6]"s"(Tb + 6*(size_t)N));
    asm volatile(
        "global_load_dwordx2 %[d0], %[vo], %[p0]\n\t"
        "global_load_dwordx2 %[d1], %[vo], %[p1]\n\t"
        "global_load_dwordx2 %[d2], %[vo], %[p2]\n\t"
        "global_load_dwordx2 %[d3], %[vo], %[p3]\n\t"
        "global_load_dwordx2 %[d4], %[vo], %[p4]\n\t"
        "global_load_dwordx2 %[d5], %[vo], %[p5]\n\t"
        "global_load_dwordx2 %[d6], %[vo], %[p6]\n\t"
        : [d0]"=v"(tv[7]), [d1]"=v"(tv[8]), [d2]"=v"(tv[9]), [d3]"=v"(tv[10]),
          [d4]"=v"(tv[11]), [d5]"=v"(tv[12]), [d6]"=v"(tv[13])
        : [vo]"v"(voff),
          [p0]"s"(Tb + 7*(size_t)N), [p1]"s"(Tb + 8*(size_t)N),
          [p2]"s"(Tb + 9*(size_t)N), [p3]"s"(Tb + 10*(size_t)N),
          [p4]"s"(Tb + 11*(size_t)N), [p5]"s"(Tb + 12*(size_t)N),
          [p6]"s"(Tb + 13*(size_t)N));

    int2 g = *reinterpret_cast<const int2*>(gt + v0);

    asm volatile("s_waitcnt vmcnt(0)" ::: "memory");
    __builtin_amdgcn_sched_barrier(0);

    float Zs0 = 0.f, Zt0 = 0.f, At0 = 0.f, As0 = 0.f;
    float Zs1 = 0.f, Zt1 = 0.f, At1 = 0.f, As1 = 0.f;
#pragma unroll
    for (int c = 0; c < NCLS; ++c) {
        float et0 = __expf(tv[c].x), et1 = __expf(tv[c].y);
        Zt0 += et0;                     Zt1 += et1;
        At0 = fmaf(et0, tv[c].x, At0);  At1 = fmaf(et1, tv[c].y, At1);
        As0 = fmaf(et0, sv[c].x, As0);  As1 = fmaf(et1, sv[c].y, As1);
        Zs0 += __expf(sv[c].x);         Zs1 += __expf(sv[c].y);
    }
    float kl0 = (At0 - As0) / Zt0 - __logf(Zt0) + __logf(Zs0);
    float kl1 = (At1 - As1) / Zt1 - __logf(Zt1) + __logf(Zs1);

    int c0 = min(max(g.x, 0), NCLS - 1);
    int c1 = min(max(g.y, 0), NCLS - 1);

    atomicAdd(&lsum[wave][c0], kl0);
    atomicAdd(&lsum[wave][c1], kl1);
    // Counts: ballot + popcount, no atomics.
#pragma unroll
    for (int c = 0; c < NCLS; ++c) {
        int nvc = __popcll(__ballot(c0 == c)) + __popcll(__ballot(c1 == c));
        if (lane == 0) lcnt[wave][c] = nvc;
    }

    __syncthreads();
    // Only 14 bins live per block (b uniform): 28 global atomics total.
    if (tid < NCLS) {
        float s = lsum[0][tid] + lsum[1][tid] + lsum[2][tid] + lsum[3][tid];
        int nn = lcnt[0][tid] + lcnt[1][tid] + lcnt[2][tid] + lcnt[3][tid];
        const int slot = blockIdx.x & (KSPREAD - 1);
        const int bin = b * NCLS + tid;
        atomicAdd(&fsum[bin * KSPREAD + slot], s);
        atomicAdd(&fcnt[bin * KSPREAD + slot], nn);
    }
}

__global__ void kd15_final(const float* __restrict__ fsum,
                           const int* __restrict__ fcnt,
                           float* __restrict__ out) {
    __shared__ float terms[64];
    const int t = threadIdx.x;
    float term = 0.0f;
    if (t < NUM_BINS) {
        const float4* fp = reinterpret_cast<const float4*>(fsum + t * KSPREAD);
        const int4* cp = reinterpret_cast<const int4*>(fcnt + t * KSPREAD);
        float s = 0.0f; int n = 0;
#pragma unroll
        for (int i = 0; i < KSPREAD / 4; ++i) {   // fully unrolled: 64 indep loads
            float4 v = fp[i]; s += (v.x + v.y) + (v.z + v.w);
            int4 c = cp[i];   n += (c.x + c.y) + (c.z + c.w);
        }
        const int cls = t % NCLS;   // bin = b*NCLS + cls
        if (cls != 0 && n > 0) term = s / ((float)NCLS * (float)n);
    }
    terms[t] = term;
    __syncthreads();
    if (t == 0) {
        float loss = 0.0f;
#pragma unroll
        for (int i = 0; i < 64; ++i) loss += terms[i];
        out[0] = loss;   // TAU^2 = 1, LOSS_WEIGHT = 1
    }
}

extern "C" void kernel_launch(void* const* d_in, const int* in_sizes, int n_in,
                              void* d_out, int out_size, void* d_ws, size_t ws_size,
                              hipStream_t stream) {
    const float* S = (const float*)d_in[0];
    const float* T = (const float*)d_in[1];
    const int* gt = (const int*)d_in[2];
    float* out = (float*)d_out;

    float* fsum = (float*)d_ws;
    int* fcnt = (int*)((char*)d_ws + NUM_BINS * KSPREAD * sizeof(float));

    const int totalVox = in_sizes[2];       // 1,769,472 = 3456 * 512
    const int N = totalVox / BATCH;         // 884,736 (divisible by 512)

    const int block = 256;
    const int grid = totalVox / (block * 2);  // 3456 blocks, 2 voxels/thread

    kd15_zero<<<(NUM_BINS * KSPREAD) / 256, 256, 0, stream>>>(fsum, fcnt);  // 14 blocks
    kd15_kl<<<grid, block, 0, stream>>>(S, T, gt, fsum, fcnt, N);
    kd15_final<<<1, 64, 0, stream>>>(fsum, fcnt, out);
}